// Round 8
// baseline (47.349 us; speedup 1.0000x reference)
//
#include <hip/hip_runtime.h>
#include <hip/hip_bf16.h>

// MEASUREMENT ROUND: identical kernels to round 7; k2 launched TWICE (idempotent:
// reads adj/yF/bias, writes out deterministically). total = k1 + k2_cold + k2_warm,
// combined with round 7's k1 + k2 = 28.8 pins the per-kernel split.
//
// out = leaky( rowscale(adj) @ X @ W^T + b ),  B=16, N=1024, F_IN=F_OUT=128
// k1: Y = X @ W^T -> MFMA-B-fragment layout (512-elem fragments), grid 256.
// k2: 64-row blocks (grid 256 = 1 block/CU), block 512 = 8 waves (2/SIMD).
//     Both operands staged via global_load_lds, double-buffered, K-step 128.

typedef __attribute__((ext_vector_type(8))) __bf16 bf16x8;
typedef __attribute__((ext_vector_type(4))) float f32x4;

#define GLD16(gp, lp) __builtin_amdgcn_global_load_lds( \
    (const __attribute__((address_space(1))) unsigned int*)(gp), \
    (__attribute__((address_space(3))) unsigned int*)(lp), 16, 0, 0)

__device__ __forceinline__ unsigned f2bf_pk(float lo, float hi) {
    union { float f; unsigned u; } a, b;
    a.f = lo; b.f = hi;
    unsigned ra = (a.u + 0x7FFFu + ((a.u >> 16) & 1u)) >> 16;
    unsigned rb = (b.u + 0x7FFFu + ((b.u >> 16) & 1u)) & 0xFFFF0000u;
    return ra | rb;
}

__device__ __forceinline__ bf16x8 cvt8(const f32x4& a, const f32x4& b) {
    union { unsigned u[4]; bf16x8 v; } r;
    r.u[0] = f2bf_pk(a.x, a.y);
    r.u[1] = f2bf_pk(a.z, a.w);
    r.u[2] = f2bf_pk(b.x, b.y);
    r.u[3] = f2bf_pk(b.z, b.w);
    return r.v;
}

// ---------------- Kernel 1: Y = X @ W^T -> fragment layout ----------------
// grid 256 (16 batches x 16 row-blocks of 64), block 256 (4 waves, each 16 rows x 128 o)
__global__ __launch_bounds__(256, 2)
void k1_xw(const float* __restrict__ x, const float* __restrict__ W,
           unsigned short* __restrict__ yF)
{
    __shared__ unsigned short Ax[64 * 128];   // X tile [m][f] bf16, rows 256B, swizzled
    __shared__ unsigned short Bw[128 * 128];  // W      [o][f] bf16, rows 256B, swizzled

    const int t   = threadIdx.x;
    const int bid = blockIdx.x;
    const int xcd = bid & 7;
    const int j   = bid >> 3;
    const int b   = xcd * 2 + (j >> 4);
    const int m0  = (j & 15) << 6;
    const float* xb = x + (((long)b << 10) + m0) * 128;

#pragma unroll
    for (int i = 0; i < 8; ++i) {
        int e = i * 1024 + t * 4;
        int r = e >> 7, f = e & 127;
        f32x4 v = *(const f32x4*)(xb + (long)r * 128 + f);
        int c = f >> 3;
        int byte = r * 256 + (((c ^ (r & 7)) << 4) | ((f & 7) << 1));
        uint2 pk; pk.x = f2bf_pk(v.x, v.y); pk.y = f2bf_pk(v.z, v.w);
        *(uint2*)((char*)Ax + byte) = pk;
    }
#pragma unroll
    for (int i = 0; i < 16; ++i) {
        int e = i * 1024 + t * 4;
        int r = e >> 7, f = e & 127;
        f32x4 v = *(const f32x4*)(W + r * 128 + f);
        int c = f >> 3;
        int byte = r * 256 + (((c ^ (r & 7)) << 4) | ((f & 7) << 1));
        uint2 pk; pk.x = f2bf_pk(v.x, v.y); pk.y = f2bf_pk(v.z, v.w);
        *(uint2*)((char*)Bw + byte) = pk;
    }
    __syncthreads();

    const int lane = t & 63, w = t >> 6;
    const int lrow = lane & 15, lq = lane >> 4;

    bf16x8 af[4];
#pragma unroll
    for (int kk = 0; kk < 4; ++kk) {
        int r = w * 16 + lrow;
        int c = kk * 4 + lq;
        af[kk] = *(const bf16x8*)((const char*)Ax + r * 256 + ((c ^ (r & 7)) << 4));
    }

    f32x4 zero = {0.f, 0.f, 0.f, 0.f};
    f32x4 acc[8] = {zero, zero, zero, zero, zero, zero, zero, zero};
#pragma unroll
    for (int nf = 0; nf < 8; ++nf) {
#pragma unroll
        for (int kk = 0; kk < 4; ++kk) {
            int o = nf * 16 + lrow;
            int c = kk * 4 + lq;
            bf16x8 bfrag = *(const bf16x8*)((const char*)Bw + o * 256 + ((c ^ (o & 7)) << 4));
            acc[nf] = __builtin_amdgcn_mfma_f32_16x16x32_bf16(af[kk], bfrag, acc[nf], 0, 0, 0);
        }
    }

    // lane holds Y[m = m0 + w*16 + lq*4 + i][o = nf*16 + lrow]
    {
        const int ks = (m0 >> 5) + (w >> 1);
        const int q  = (w & 1) * 2 + (lq >> 1);
        const int jb = (lq & 1) * 4;
#pragma unroll
        for (int nf = 0; nf < 8; ++nf) {
            uint2 pk;
            pk.x = f2bf_pk(acc[nf][0], acc[nf][1]);
            pk.y = f2bf_pk(acc[nf][2], acc[nf][3]);
            long off = (((long)((b * 32 + ks) * 8 + nf)) << 9) + (q * 16 + lrow) * 8 + jb;
            *(uint2*)(yF + off) = pk;
        }
    }
}

// ---------------- Kernel 2: out = leaky( invdeg * (adj @ Y) + bias ) ----------------
__global__ __launch_bounds__(512, 2)
void k2_agg(const float* __restrict__ adj, const unsigned short* __restrict__ yF,
            const float* __restrict__ bias, float* __restrict__ out)
{
    __shared__ float          bufA[2][64 * 128];    // 2 x 32KB fp32 adj tiles (swizzled chunks)
    __shared__ unsigned short bufY[2][32 * 512];    // 2 x 32KB bf16 Y fragments

    const int bid = blockIdx.x;
    const int xcd = bid & 7;
    const int j   = bid >> 3;             // 0..31
    const int b   = xcd * 2 + (j >> 4);   // each XCD: 2 batches
    const int n0  = (j & 15) << 6;        // 64-row tile

    const int t = threadIdx.x;
    const int lane = t & 63, w = t >> 6;  // w = 0..7
    const int h = w >> 1, oc = w & 1;     // rowgroup, colhalf
    const int lrow = lane & 15, lq = lane >> 4;

    const float* adjb = adj + ((long)b << 20);  // batch base (1024*1024)

    const int srow = (lane >> 5);          // adj: sub-row within instr (0/1)
    const int ssc  = lane & 31;            // adj: stored chunk index

    f32x4 zero = {0.f, 0.f, 0.f, 0.f};
    f32x4 acc[4] = {zero, zero, zero, zero};
    float dsum = 0.f;

#define STAGE(BUF, S)                                                                  \
    do {                                                                               \
        if (w < 4) {                                                                   \
            _Pragma("unroll")                                                          \
            for (int i = 0; i < 8; ++i) {                                              \
                int rl = w * 16 + 2 * i + srow;                                        \
                const float* g = adjb + ((long)(n0 + rl) << 10) + (S) * 128            \
                               + ((ssc ^ (rl & 7)) << 2);                              \
                GLD16(g, &bufA[BUF][(w * 16 + 2 * i) * 128]);                          \
            }                                                                          \
        } else {                                                                       \
            const int ks = w - 4;                                                      \
            _Pragma("unroll")                                                          \
            for (int i = 0; i < 8; ++i) {                                              \
                const unsigned short* g = yF                                           \
                    + (((long)((b * 32 + (S) * 4 + ks) * 8 + i)) << 9) + lane * 8;     \
                GLD16(g, &bufY[BUF][(ks * 8 + i) << 9]);                               \
            }                                                                          \
        }                                                                              \
    } while (0)

    STAGE(0, 0);
    __syncthreads();

    for (int s = 0; s < 8; ++s) {
        const int cur = s & 1;
        if (s < 7) STAGE(cur ^ 1, s + 1);

        const int row = h * 16 + lrow;
        const int rx  = row & 7;
#pragma unroll
        for (int kk = 0; kk < 4; ++kk) {
            const int c0 = kk * 8 + lq * 2;
            f32x4 a0 = *(const f32x4*)&bufA[cur][row * 128 + ((c0 ^ rx) << 2)];
            f32x4 a1 = *(const f32x4*)&bufA[cur][row * 128 + (((c0 + 1) ^ rx) << 2)];
            dsum += a0.x + a0.y + a0.z + a0.w + a1.x + a1.y + a1.z + a1.w;
            bf16x8 a = cvt8(a0, a1);
#pragma unroll
            for (int n = 0; n < 4; ++n) {
                const int ot = oc * 4 + n;
                bf16x8 bb = *(const bf16x8*)&bufY[cur][((kk * 8 + ot) << 9) + lane * 8];
                acc[n] = __builtin_amdgcn_mfma_f32_16x16x32_bf16(a, bb, acc[n], 0, 0, 0);
            }
        }
        __syncthreads();
    }

    dsum += __shfl_xor(dsum, 16, 64);
    dsum += __shfl_xor(dsum, 32, 64);
    float invd[4];
#pragma unroll
    for (int i = 0; i < 4; ++i)
        invd[i] = 1.0f / __shfl(dsum, lq * 4 + i, 64);

#pragma unroll
    for (int n = 0; n < 4; ++n) {
        const int o = (oc * 4 + n) * 16 + lrow;
        const float bv = bias[o];
#pragma unroll
        for (int i = 0; i < 4; ++i) {
            const int r = n0 + h * 16 + lq * 4 + i;
            float v = acc[n][i] * invd[i] + bv;
            v = (v >= 0.f) ? v : 0.01f * v;
            out[(((long)(b * 1024 + r)) << 7) + o] = v;
        }
    }
#undef STAGE
}

extern "C" void kernel_launch(void* const* d_in, const int* in_sizes, int n_in,
                              void* d_out, int out_size, void* d_ws, size_t ws_size,
                              hipStream_t stream) {
    const float* node = (const float*)d_in[0];   // [16,1024,128]
    const float* adj  = (const float*)d_in[1];   // [16,1024,1024]
    const float* W    = (const float*)d_in[2];   // [128,128]
    const float* bias = (const float*)d_in[3];   // [128]
    float* out = (float*)d_out;                  // [16,1024,128]
    unsigned short* yF = (unsigned short*)d_ws;  // 16*32*8*512 bf16 = 4 MB scratch

    k1_xw<<<dim3(256), dim3(256), 0, stream>>>(node, W, yF);
    // k2 launched twice (idempotent) to measure the k1/k2 split:
    // total = k1 + k2_cold + k2_warm; round 7 total = k1 + k2 = 28.8 us.
    k2_agg<<<dim3(256), dim3(512), 0, stream>>>(adj, yF, bias, out);
    k2_agg<<<dim3(256), dim3(512), 0, stream>>>(adj, yF, bias, out);
}

// Round 9
// 36.151 us; speedup vs baseline: 1.3098x; 1.3098x over previous
//
#include <hip/hip_runtime.h>
#include <hip/hip_bf16.h>

// out = leaky( rowscale(adj) @ X @ W^T + b ),  B=16, N=1024, F_IN=F_OUT=128
// k1: Y = X @ W^T -> MFMA-B-fragment layout. grid 1024 (16-row tiles), 4 blocks/CU.
// k2: 64-row blocks (grid 256 = 1 block/CU), block 512 = 8 waves.
//     global_load_lds double-buffer with COUNTED vmcnt(8) + raw s_barrier
//     (never drains the prefetch); each wave stages 4 adj + 4 Y loads (balanced).
//
// yF fragment layout: fragment (b, ks, ot) at elem offset ((b*32+ks)*8+ot)*512,
//   lane l elems j=0..7 at +l*8+j hold Y[m = ks*32 + (l>>4)*8 + j][o = ot*16 + (l&15)]

typedef __attribute__((ext_vector_type(8))) __bf16 bf16x8;
typedef __attribute__((ext_vector_type(4))) float f32x4;

#define GLD16(gp, lp) __builtin_amdgcn_global_load_lds( \
    (const __attribute__((address_space(1))) unsigned int*)(gp), \
    (__attribute__((address_space(3))) unsigned int*)(lp), 16, 0, 0)

#define WAITV8()  do { asm volatile("s_waitcnt vmcnt(8)" ::: "memory"); \
                       __builtin_amdgcn_sched_barrier(0); } while (0)
#define WAITV0()  do { asm volatile("s_waitcnt vmcnt(0)" ::: "memory"); \
                       __builtin_amdgcn_sched_barrier(0); } while (0)
#define BAR()     __builtin_amdgcn_s_barrier()

__device__ __forceinline__ unsigned f2bf_pk(float lo, float hi) {
    union { float f; unsigned u; } a, b;
    a.f = lo; b.f = hi;
    unsigned ra = (a.u + 0x7FFFu + ((a.u >> 16) & 1u)) >> 16;
    unsigned rb = (b.u + 0x7FFFu + ((b.u >> 16) & 1u)) & 0xFFFF0000u;
    return ra | rb;
}

__device__ __forceinline__ bf16x8 cvt8(const f32x4& a, const f32x4& b) {
    union { unsigned u[4]; bf16x8 v; } r;
    r.u[0] = f2bf_pk(a.x, a.y);
    r.u[1] = f2bf_pk(a.z, a.w);
    r.u[2] = f2bf_pk(b.x, b.y);
    r.u[3] = f2bf_pk(b.z, b.w);
    return r.v;
}

// ---------------- Kernel 1: Y = X @ W^T -> fragment layout ----------------
// grid 1024 (16 batches x 64 row-blocks of 16), block 256 (4 waves), 4 blocks/CU.
// Wave w computes o-tiles {2w, 2w+1} for all 16 rows (8 MFMA/wave).
__global__ __launch_bounds__(256, 4)
void k1_xw(const float* __restrict__ x, const float* __restrict__ W,
           unsigned short* __restrict__ yF)
{
    __shared__ unsigned short Ax[16 * 128];   // X tile [m][f] bf16, rows 256B, swizzled
    __shared__ unsigned short Bw[128 * 128];  // W      [o][f] bf16, rows 256B, swizzled

    const int t  = threadIdx.x;
    const int wg = blockIdx.x;
    const int b  = wg >> 6;
    const int m0 = (wg & 63) << 4;
    const float* xb = x + (((long)b << 10) + m0) * 128;

#pragma unroll
    for (int i = 0; i < 2; ++i) {
        int e = i * 1024 + t * 4;
        int r = e >> 7, f = e & 127;
        f32x4 v = *(const f32x4*)(xb + (long)r * 128 + f);
        int c = f >> 3;
        int byte = r * 256 + (((c ^ (r & 7)) << 4) | ((f & 7) << 1));
        uint2 pk; pk.x = f2bf_pk(v.x, v.y); pk.y = f2bf_pk(v.z, v.w);
        *(uint2*)((char*)Ax + byte) = pk;
    }
#pragma unroll
    for (int i = 0; i < 16; ++i) {
        int e = i * 1024 + t * 4;
        int r = e >> 7, f = e & 127;
        f32x4 v = *(const f32x4*)(W + r * 128 + f);
        int c = f >> 3;
        int byte = r * 256 + (((c ^ (r & 7)) << 4) | ((f & 7) << 1));
        uint2 pk; pk.x = f2bf_pk(v.x, v.y); pk.y = f2bf_pk(v.z, v.w);
        *(uint2*)((char*)Bw + byte) = pk;
    }
    __syncthreads();

    const int lane = t & 63, w = t >> 6;
    const int lrow = lane & 15, lq = lane >> 4;

    bf16x8 af[4];
#pragma unroll
    for (int kk = 0; kk < 4; ++kk) {
        int r = lrow;
        int c = kk * 4 + lq;
        af[kk] = *(const bf16x8*)((const char*)Ax + r * 256 + ((c ^ (r & 7)) << 4));
    }

    f32x4 zero = {0.f, 0.f, 0.f, 0.f};
    f32x4 acc[2] = {zero, zero};
#pragma unroll
    for (int nf = 0; nf < 2; ++nf) {
#pragma unroll
        for (int kk = 0; kk < 4; ++kk) {
            int o = (w * 2 + nf) * 16 + lrow;
            int c = kk * 4 + lq;
            bf16x8 bfrag = *(const bf16x8*)((const char*)Bw + o * 256 + ((c ^ (o & 7)) << 4));
            acc[nf] = __builtin_amdgcn_mfma_f32_16x16x32_bf16(af[kk], bfrag, acc[nf], 0, 0, 0);
        }
    }

    // lane holds Y[m = m0 + lq*4 + i][o = (2w+nf)*16 + lrow]
    {
        const int ks = m0 >> 5;
        const int q  = ((m0 >> 4) & 1) * 2 + (lq >> 1);
        const int jb = (lq & 1) * 4;
#pragma unroll
        for (int nf = 0; nf < 2; ++nf) {
            int ot = w * 2 + nf;
            uint2 pk;
            pk.x = f2bf_pk(acc[nf][0], acc[nf][1]);
            pk.y = f2bf_pk(acc[nf][2], acc[nf][3]);
            long off = (((long)((b * 32 + ks) * 8 + ot)) << 9) + (q * 16 + lrow) * 8 + jb;
            *(uint2*)(yF + off) = pk;
        }
    }
}

// ---------------- Kernel 2: out = leaky( invdeg * (adj @ Y) + bias ) ----------------
// grid 256 (1 block/CU), block 512 (8 waves). Counted-vmcnt double-buffer pipeline:
// per step: issue 8 GLD16 for step s+1 -> vmcnt(8) -> raw barrier -> compute ->
// raw barrier. Prefetch stays in flight across barriers (never drained).
__global__ __launch_bounds__(512, 2)
void k2_agg(const float* __restrict__ adj, const unsigned short* __restrict__ yF,
            const float* __restrict__ bias, float* __restrict__ out)
{
    __shared__ float          bufA[2][64 * 128];    // 2 x 32KB fp32 adj tiles (swizzled chunks)
    __shared__ unsigned short bufY[2][32 * 512];    // 2 x 32KB bf16 Y fragments

    const int bid = blockIdx.x;
    const int xcd = bid & 7;
    const int j   = bid >> 3;             // 0..31
    const int b   = xcd * 2 + (j >> 4);   // each XCD: 2 batches
    const int n0  = (j & 15) << 6;        // 64-row tile

    const int t = threadIdx.x;
    const int lane = t & 63, w = t >> 6;  // w = 0..7
    const int h = w >> 1, oc = w & 1;     // rowgroup, colhalf
    const int lrow = lane & 15, lq = lane >> 4;

    const float* adjb = adj + ((long)b << 20);

    const int srow = (lane >> 5);          // adj: sub-row within instr (0/1)
    const int ssc  = lane & 31;            // adj: stored chunk index

    f32x4 zero = {0.f, 0.f, 0.f, 0.f};
    f32x4 acc[4] = {zero, zero, zero, zero};
    float dsum = 0.f;

    // wave w stages: adj rows [w*8, w*8+8) (4 GLD16, HBM) + Y frags [w*4, w*4+4) (4, L2)
#define STAGE(BUF, S)                                                                  \
    do {                                                                               \
        _Pragma("unroll")                                                              \
        for (int i = 0; i < 4; ++i) {                                                  \
            int rl = w * 8 + 2 * i + srow;                                             \
            const float* g = adjb + ((long)(n0 + rl) << 10) + (S) * 128                \
                           + ((ssc ^ (rl & 7)) << 2);                                  \
            GLD16(g, &bufA[BUF][(w * 8 + 2 * i) * 128]);                               \
        }                                                                              \
        _Pragma("unroll")                                                              \
        for (int i2 = 0; i2 < 4; ++i2) {                                               \
            int f = w * 4 + i2;                                                        \
            const unsigned short* g = yF                                               \
                + (((long)((b * 32 + (S) * 4 + (f >> 3)) * 8 + (f & 7))) << 9)         \
                + lane * 8;                                                            \
            GLD16(g, &bufY[BUF][f << 9]);                                              \
        }                                                                              \
    } while (0)

#define COMPUTE(BUF)                                                                   \
    do {                                                                               \
        const int row = h * 16 + lrow;                                                 \
        const int rx  = row & 7;                                                       \
        _Pragma("unroll")                                                              \
        for (int kk = 0; kk < 4; ++kk) {                                               \
            const int c0 = kk * 8 + lq * 2;                                            \
            f32x4 a0 = *(const f32x4*)&bufA[BUF][row * 128 + ((c0 ^ rx) << 2)];        \
            f32x4 a1 = *(const f32x4*)&bufA[BUF][row * 128 + (((c0 + 1) ^ rx) << 2)];  \
            dsum += a0.x + a0.y + a0.z + a0.w + a1.x + a1.y + a1.z + a1.w;             \
            bf16x8 a = cvt8(a0, a1);                                                   \
            _Pragma("unroll")                                                          \
            for (int n = 0; n < 4; ++n) {                                              \
                const int ot = oc * 4 + n;                                             \
                bf16x8 bb = *(const bf16x8*)&bufY[BUF][((kk * 8 + ot) << 9) + lane * 8];\
                acc[n] = __builtin_amdgcn_mfma_f32_16x16x32_bf16(a, bb, acc[n], 0, 0, 0);\
            }                                                                          \
        }                                                                              \
    } while (0)

    STAGE(0, 0);                 // outstanding: 8
#pragma unroll
    for (int s = 0; s < 8; ++s) {
        const int cur = s & 1;
        if (s < 7) {
            STAGE(cur ^ 1, s + 1);   // outstanding: <=16
            WAITV8();                // stage s arrived; next 8 stay in flight
        } else {
            WAITV0();
        }
        BAR();                       // raw barrier: no vmcnt drain
        COMPUTE(cur);
        BAR();                       // protect buf[cur] before step s+1 overwrites
    }

    dsum += __shfl_xor(dsum, 16, 64);
    dsum += __shfl_xor(dsum, 32, 64);
    float invd[4];
#pragma unroll
    for (int i = 0; i < 4; ++i)
        invd[i] = 1.0f / __shfl(dsum, lq * 4 + i, 64);

#pragma unroll
    for (int n = 0; n < 4; ++n) {
        const int o = (oc * 4 + n) * 16 + lrow;
        const float bv = bias[o];
#pragma unroll
        for (int i = 0; i < 4; ++i) {
            const int r = n0 + h * 16 + lq * 4 + i;
            float v = acc[n][i] * invd[i] + bv;
            v = (v >= 0.f) ? v : 0.01f * v;
            out[(((long)(b * 1024 + r)) << 7) + o] = v;
        }
    }
#undef STAGE
#undef COMPUTE
}

extern "C" void kernel_launch(void* const* d_in, const int* in_sizes, int n_in,
                              void* d_out, int out_size, void* d_ws, size_t ws_size,
                              hipStream_t stream) {
    const float* node = (const float*)d_in[0];   // [16,1024,128]
    const float* adj  = (const float*)d_in[1];   // [16,1024,1024]
    const float* W    = (const float*)d_in[2];   // [128,128]
    const float* bias = (const float*)d_in[3];   // [128]
    float* out = (float*)d_out;                  // [16,1024,128]
    unsigned short* yF = (unsigned short*)d_ws;  // 16*32*8*512 bf16 = 4 MB scratch

    k1_xw<<<dim3(1024), dim3(256), 0, stream>>>(node, W, yF);
    k2_agg<<<dim3(256), dim3(512), 0, stream>>>(adj, yF, bias, out);
}

// Round 10
// 30.400 us; speedup vs baseline: 1.5575x; 1.1892x over previous
//
#include <hip/hip_runtime.h>
#include <hip/hip_bf16.h>

// out = leaky( rowscale(adj) @ X @ W^T + b ),  B=16, N=1024, F_IN=F_OUT=128
// k1: Y = X @ W^T -> MFMA-B-fragment layout. grid 1024 (16-row tiles), 4 blocks/CU.
// k2: 64-row blocks (grid 256 = 1 block/CU), block 512 = 8 waves.
//     Counted-vmcnt double-buffer: per step issue next 8 global_load_lds,
//     s_waitcnt vmcnt(8), raw s_barrier (prefetch never drained), compute, barrier.
//     ROLLED loop + pointer-increment addressing + launch_bounds(512,1): no spills.
//
// yF fragment layout: fragment (b, ks, ot) at elem offset ((b*32+ks)*8+ot)*512,
//   lane l elems j=0..7 at +l*8+j hold Y[m = ks*32 + (l>>4)*8 + j][o = ot*16 + (l&15)]

typedef __attribute__((ext_vector_type(8))) __bf16 bf16x8;
typedef __attribute__((ext_vector_type(4))) float f32x4;

#define GLD16(gp, lp) __builtin_amdgcn_global_load_lds( \
    (const __attribute__((address_space(1))) unsigned int*)(gp), \
    (__attribute__((address_space(3))) unsigned int*)(lp), 16, 0, 0)

#define WAITV8()  do { asm volatile("s_waitcnt vmcnt(8)" ::: "memory"); \
                       __builtin_amdgcn_sched_barrier(0); } while (0)
#define WAITV0()  do { asm volatile("s_waitcnt vmcnt(0)" ::: "memory"); \
                       __builtin_amdgcn_sched_barrier(0); } while (0)
#define BARF()    do { __builtin_amdgcn_s_barrier(); \
                       __builtin_amdgcn_sched_barrier(0); } while (0)

__device__ __forceinline__ unsigned f2bf_pk(float lo, float hi) {
    union { float f; unsigned u; } a, b;
    a.f = lo; b.f = hi;
    unsigned ra = (a.u + 0x7FFFu + ((a.u >> 16) & 1u)) >> 16;
    unsigned rb = (b.u + 0x7FFFu + ((b.u >> 16) & 1u)) & 0xFFFF0000u;
    return ra | rb;
}

__device__ __forceinline__ bf16x8 cvt8(const f32x4& a, const f32x4& b) {
    union { unsigned u[4]; bf16x8 v; } r;
    r.u[0] = f2bf_pk(a.x, a.y);
    r.u[1] = f2bf_pk(a.z, a.w);
    r.u[2] = f2bf_pk(b.x, b.y);
    r.u[3] = f2bf_pk(b.z, b.w);
    return r.v;
}

// ---------------- Kernel 1: Y = X @ W^T -> fragment layout ----------------
// grid 1024 (16 batches x 64 row-blocks of 16), block 256 (4 waves), 4 blocks/CU.
__global__ __launch_bounds__(256, 4)
void k1_xw(const float* __restrict__ x, const float* __restrict__ W,
           unsigned short* __restrict__ yF)
{
    __shared__ unsigned short Ax[16 * 128];   // X tile [m][f] bf16, rows 256B, swizzled
    __shared__ unsigned short Bw[128 * 128];  // W      [o][f] bf16, rows 256B, swizzled

    const int t  = threadIdx.x;
    const int wg = blockIdx.x;
    const int b  = wg >> 6;
    const int m0 = (wg & 63) << 4;
    const float* xb = x + (((long)b << 10) + m0) * 128;

#pragma unroll
    for (int i = 0; i < 2; ++i) {
        int e = i * 1024 + t * 4;
        int r = e >> 7, f = e & 127;
        f32x4 v = *(const f32x4*)(xb + (long)r * 128 + f);
        int c = f >> 3;
        int byte = r * 256 + (((c ^ (r & 7)) << 4) | ((f & 7) << 1));
        uint2 pk; pk.x = f2bf_pk(v.x, v.y); pk.y = f2bf_pk(v.z, v.w);
        *(uint2*)((char*)Ax + byte) = pk;
    }
#pragma unroll
    for (int i = 0; i < 16; ++i) {
        int e = i * 1024 + t * 4;
        int r = e >> 7, f = e & 127;
        f32x4 v = *(const f32x4*)(W + r * 128 + f);
        int c = f >> 3;
        int byte = r * 256 + (((c ^ (r & 7)) << 4) | ((f & 7) << 1));
        uint2 pk; pk.x = f2bf_pk(v.x, v.y); pk.y = f2bf_pk(v.z, v.w);
        *(uint2*)((char*)Bw + byte) = pk;
    }
    __syncthreads();

    const int lane = t & 63, w = t >> 6;
    const int lrow = lane & 15, lq = lane >> 4;

    bf16x8 af[4];
#pragma unroll
    for (int kk = 0; kk < 4; ++kk) {
        int r = lrow;
        int c = kk * 4 + lq;
        af[kk] = *(const bf16x8*)((const char*)Ax + r * 256 + ((c ^ (r & 7)) << 4));
    }

    f32x4 zero = {0.f, 0.f, 0.f, 0.f};
    f32x4 acc[2] = {zero, zero};
#pragma unroll
    for (int nf = 0; nf < 2; ++nf) {
#pragma unroll
        for (int kk = 0; kk < 4; ++kk) {
            int o = (w * 2 + nf) * 16 + lrow;
            int c = kk * 4 + lq;
            bf16x8 bfrag = *(const bf16x8*)((const char*)Bw + o * 256 + ((c ^ (o & 7)) << 4));
            acc[nf] = __builtin_amdgcn_mfma_f32_16x16x32_bf16(af[kk], bfrag, acc[nf], 0, 0, 0);
        }
    }

    // lane holds Y[m = m0 + lq*4 + i][o = (2w+nf)*16 + lrow]
    {
        const int ks = m0 >> 5;
        const int q  = ((m0 >> 4) & 1) * 2 + (lq >> 1);
        const int jb = (lq & 1) * 4;
#pragma unroll
        for (int nf = 0; nf < 2; ++nf) {
            int ot = w * 2 + nf;
            uint2 pk;
            pk.x = f2bf_pk(acc[nf][0], acc[nf][1]);
            pk.y = f2bf_pk(acc[nf][2], acc[nf][3]);
            long off = (((long)((b * 32 + ks) * 8 + ot)) << 9) + (q * 16 + lrow) * 8 + jb;
            *(uint2*)(yF + off) = pk;
        }
    }
}

// ---------------- Kernel 2: out = leaky( invdeg * (adj @ Y) + bias ) ----------------
__global__ __launch_bounds__(512, 1)
void k2_agg(const float* __restrict__ adj, const unsigned short* __restrict__ yF,
            const float* __restrict__ bias, float* __restrict__ out)
{
    __shared__ float          bufA[2][64 * 128];    // 2 x 32KB fp32 adj tiles (swizzled chunks)
    __shared__ unsigned short bufY[2][32 * 512];    // 2 x 32KB bf16 Y fragments

    const int bid = blockIdx.x;
    const int xcd = bid & 7;
    const int j   = bid >> 3;             // 0..31
    const int b   = xcd * 2 + (j >> 4);   // each XCD: 2 batches
    const int n0  = (j & 15) << 6;        // 64-row tile

    const int t = threadIdx.x;
    const int lane = t & 63, w = t >> 6;  // w = 0..7
    const int h = w >> 1, oc = w & 1;     // rowgroup, colhalf
    const int lrow = lane & 15, lq = lane >> 4;

    const float* adjb = adj + ((long)b << 20);
    const int srow = (lane >> 5);          // adj: sub-row within instr (0/1)
    const int ssc  = lane & 31;            // adj: stored chunk index

    // per-wave staging base pointers (computed once; step offset added in-loop)
    const float* ag[4];
    int adst[4];
#pragma unroll
    for (int i = 0; i < 4; ++i) {
        int rl = w * 8 + 2 * i + srow;
        ag[i]   = adjb + ((long)(n0 + rl) << 10) + ((ssc ^ (rl & 7)) << 2);
        adst[i] = (w * 8 + 2 * i) * 128;
    }
    const unsigned short* yg[4];
    int ydst[4];
#pragma unroll
    for (int i = 0; i < 4; ++i) {
        int f = w * 4 + i;
        yg[i]   = yF + (((long)((b * 32 + (f >> 3)) * 8 + (f & 7))) << 9) + lane * 8;
        ydst[i] = f << 9;
    }

    f32x4 zero = {0.f, 0.f, 0.f, 0.f};
    f32x4 acc[4] = {zero, zero, zero, zero};
    float dsum = 0.f;

#define STAGE(BUF, S)                                                   \
    do {                                                                \
        _Pragma("unroll")                                               \
        for (int i = 0; i < 4; ++i)                                     \
            GLD16(ag[i] + (S) * 128, &bufA[BUF][adst[i]]);              \
        _Pragma("unroll")                                               \
        for (int i = 0; i < 4; ++i)                                     \
            GLD16(yg[i] + (long)(S) * 16384, &bufY[BUF][ydst[i]]);      \
    } while (0)

    const int row = h * 16 + lrow;
    const int rx  = row & 7;

    STAGE(0, 0);                 // outstanding: 8
    int cur = 0;
#pragma unroll 2
    for (int s = 0; s < 8; ++s) {
        if (s < 7) {
            STAGE(cur ^ 1, s + 1);   // outstanding: <=16
            WAITV8();                // stage s arrived; next 8 stay in flight
        } else {
            WAITV0();
        }
        BARF();                      // raw barrier (no vmcnt drain) + sched fence
#pragma unroll
        for (int kk = 0; kk < 4; ++kk) {
            const int c0 = kk * 8 + lq * 2;
            f32x4 a0 = *(const f32x4*)&bufA[cur][row * 128 + ((c0 ^ rx) << 2)];
            f32x4 a1 = *(const f32x4*)&bufA[cur][row * 128 + (((c0 + 1) ^ rx) << 2)];
            dsum += a0.x + a0.y + a0.z + a0.w + a1.x + a1.y + a1.z + a1.w;
            bf16x8 a = cvt8(a0, a1);
#pragma unroll
            for (int n = 0; n < 4; ++n) {
                const int ot = oc * 4 + n;
                bf16x8 bb = *(const bf16x8*)&bufY[cur][((kk * 8 + ot) << 9) + lane * 8];
                acc[n] = __builtin_amdgcn_mfma_f32_16x16x32_bf16(a, bb, acc[n], 0, 0, 0);
            }
        }
        BARF();                      // protect buf[cur] before step s+1 overwrites
        cur ^= 1;
    }
#undef STAGE

    dsum += __shfl_xor(dsum, 16, 64);
    dsum += __shfl_xor(dsum, 32, 64);
    float invd[4];
#pragma unroll
    for (int i = 0; i < 4; ++i)
        invd[i] = 1.0f / __shfl(dsum, lq * 4 + i, 64);

#pragma unroll
    for (int n = 0; n < 4; ++n) {
        const int o = (oc * 4 + n) * 16 + lrow;
        const float bv = bias[o];
#pragma unroll
        for (int i = 0; i < 4; ++i) {
            const int r = n0 + h * 16 + lq * 4 + i;
            float v = acc[n][i] * invd[i] + bv;
            v = (v >= 0.f) ? v : 0.01f * v;
            out[(((long)(b * 1024 + r)) << 7) + o] = v;
        }
    }
}

extern "C" void kernel_launch(void* const* d_in, const int* in_sizes, int n_in,
                              void* d_out, int out_size, void* d_ws, size_t ws_size,
                              hipStream_t stream) {
    const float* node = (const float*)d_in[0];   // [16,1024,128]
    const float* adj  = (const float*)d_in[1];   // [16,1024,1024]
    const float* W    = (const float*)d_in[2];   // [128,128]
    const float* bias = (const float*)d_in[3];   // [128]
    float* out = (float*)d_out;                  // [16,1024,128]
    unsigned short* yF = (unsigned short*)d_ws;  // 16*32*8*512 bf16 = 4 MB scratch

    k1_xw<<<dim3(1024), dim3(256), 0, stream>>>(node, W, yF);
    k2_agg<<<dim3(256), dim3(512), 0, stream>>>(adj, yF, bias, out);
}